// Round 10
// baseline (221.730 us; speedup 1.0000x reference)
//
#include <hip/hip_runtime.h>
#include <hip/hip_bf16.h>

#define IN_F 8192
#define OUT_F 28672
#define RANK 32
#define NGROUPS 128          // IN_F / 64
#define M_TOK 16
#define TCHUNK 16            // K-chunks for lora-t partials
#define TCK (IN_F / TCHUNK)  // 512
#define KSPLIT 4
#define KW (IN_F / KSPLIT)   // 2048 per wave
#define NSTEP (KW / 256)     // 8 supersteps of 256 k each

typedef __bf16 bf16x8 __attribute__((ext_vector_type(8)));
typedef float  f32x4  __attribute__((ext_vector_type(4)));
typedef int    i32x4  __attribute__((ext_vector_type(4)));

#define GLOBAL_AS __attribute__((address_space(1)))
#define LDS_AS    __attribute__((address_space(3)))

// ---------------------------------------------------------------------------
// Kernel 1: lora-t partials + fused x f32->bf16 cast. 16 blocks x 512 thr.
// ---------------------------------------------------------------------------
__global__ __launch_bounds__(512) void svdq_prep(
    const float* __restrict__ x, const float* __restrict__ ld,
    float* __restrict__ part, __bf16* __restrict__ xb) {
  const int c = blockIdx.x;
  const int i = threadIdx.x;

  // ---- cast slice: flat f32 [c*8192, +8192), 16 per thread ----
  {
    const int base = c * 8192 + i * 16;
    f32x4 f0 = *reinterpret_cast<const f32x4*>(x + base);
    f32x4 f1 = *reinterpret_cast<const f32x4*>(x + base + 4);
    f32x4 f2 = *reinterpret_cast<const f32x4*>(x + base + 8);
    f32x4 f3 = *reinterpret_cast<const f32x4*>(x + base + 12);
    bf16x8 v0, v1;
#pragma unroll
    for (int j = 0; j < 4; ++j) {
      v0[j] = (__bf16)f0[j]; v0[j + 4] = (__bf16)f1[j];
      v1[j] = (__bf16)f2[j]; v1[j + 4] = (__bf16)f3[j];
    }
    *reinterpret_cast<bf16x8*>(xb + base)     = v0;
    *reinterpret_cast<bf16x8*>(xb + base + 8) = v1;
  }

  // ---- tpart slice ----
  const int m = i >> 5, r = i & 31;
  const f32x4* xp = reinterpret_cast<const f32x4*>(x  + (size_t)m * IN_F + c * TCK);
  const f32x4* lp = reinterpret_cast<const f32x4*>(ld + (size_t)r * IN_F + c * TCK);
  float s = 0.f;
#pragma unroll 8
  for (int j = 0; j < TCK / 4; ++j) {
    f32x4 a = xp[j], b = lp[j];
    s += a[0]*b[0] + a[1]*b[1] + a[2]*b[2] + a[3]*b[3];
  }
  part[(size_t)c * (M_TOK * RANK) + i] = s;
}

// ---------------------------------------------------------------------------
// Kernel 2: fused dequant-GEMM + lora-up + bias, split-K x4.
// Staging: each global_load_lds reads 1 KB CONTIGUOUS from ONE q row
// (64 lanes x 16B in-row; R9 was 512 B from 2 rows). 16 instrs/superstep
// stage 16 rows x 1 KB = 16 KB into the wave's buffer. Source chunk for
// lane l of row r is l ^ (r&7) (16B units); compute reads slot c ^ (col&7)
// -> conflict-free ds_read_b128 (same involution both sides, m173/m201).
// LDS 128 KB/block (2 buf x 16 KB x 4 waves) -> 1 block/CU, 4 waves/CU;
// in-flight 4x16 KB = 64 KB/CU >> 9.2 KB latency-hiding requirement.
// Counted vmcnt(25) = 8 x-loads + 1 scale + 16 stages per window.
// grid = OUT_F/16 = 1792 blocks x 256 threads.
// ---------------------------------------------------------------------------
__global__ __launch_bounds__(256) void svdq_main(
    const __bf16* __restrict__ xb, const int* __restrict__ qw,
    const float* __restrict__ wsc, const float* __restrict__ lu,
    const float* __restrict__ bias, const float* __restrict__ part,
    float* __restrict__ out) {
  const int w     = threadIdx.x >> 6;   // wave id: K-split slice
  const int lane  = threadIdx.x & 63;
  const int col   = lane & 15;
  const int hi    = lane >> 4;
  const int obase = blockIdx.x * 16;
  const int o     = obase + col;

  __shared__ int smem[KSPLIT * 8192];   // 128 KB; wave w owns [w*8192, +8192)
  int* mybuf = smem + w * 8192;         // 2 buffers x 4096 ints (16 KB each)

  const int*    qbase = qw + (size_t)obase * IN_F + w * KW;
  const __bf16* xrow  = xb + (size_t)col * IN_F + w * KW + hi * 8;
  const float*  srow  = wsc + (size_t)o * NGROUPS + w * (KW / 64);

  // per-lane swizzled source offsets (ints) for row r: chunk = lane ^ (r&7)
  int xoff[8];
#pragma unroll
  for (int j = 0; j < 8; ++j) xoff[j] = (lane ^ j) * 4;

  // Stage superstep T (256 k per row, 16 rows = 16 KB) into buffer B.
  // Instr r: all 64 lanes read row r's [T*256 + (lane^(r&7))*4, +4) ints.
  // LDS: row r at mybuf + B*4096 + r*256 (linear, lane*4).
#define STAGE(T, B)                                                            \
  {                                                                            \
    _Pragma("unroll")                                                          \
    for (int r = 0; r < 16; ++r) {                                             \
      const int* _s = qbase + (size_t)r * IN_F + (T) * 256 + xoff[r & 7];      \
      __builtin_amdgcn_global_load_lds((const GLOBAL_AS int*)_s,               \
          (LDS_AS int*)(mybuf + (B) * 4096 + r * 256), 16, 0, 0);              \
    }                                                                          \
  }

  f32x4 acc = {0.f, 0.f, 0.f, 0.f};

  // kk=0..7: lane needs row col, source chunks c0 = kk*8+hi*2 and c0+1.
#define COMPUTE(B, AX, SC)                                                     \
  {                                                                            \
    const int* _base = mybuf + (B) * 4096 + col * 256;                         \
    const int  _sw   = col & 7;                                                \
    _Pragma("unroll")                                                          \
    for (int kk = 0; kk < 8; ++kk) {                                           \
      const int c0 = kk * 8 + hi * 2;                                          \
      i32x4 q0 = *reinterpret_cast<const i32x4*>(_base + ((c0 ^ _sw) * 4));    \
      i32x4 q1 = *reinterpret_cast<const i32x4*>(_base + (((c0 + 1) ^ _sw) * 4));\
      const float s = (SC)[kk >> 1];                                           \
      bf16x8 b;                                                                \
      _Pragma("unroll")                                                        \
      for (int j = 0; j < 4; ++j) {                                            \
        b[j]     = (__bf16)((float)q0[j] * s);                                 \
        b[j + 4] = (__bf16)((float)q1[j] * s);                                 \
      }                                                                        \
      acc = __builtin_amdgcn_mfma_f32_16x16x32_bf16((AX)[kk], b, acc, 0, 0, 0);\
    }                                                                          \
  }

#define LOADX(AX, T)                                                           \
  {                                                                            \
    _Pragma("unroll")                                                          \
    for (int kk = 0; kk < 8; ++kk)                                             \
      (AX)[kk] = *reinterpret_cast<const bf16x8*>(xrow + (T) * 256 + kk * 32); \
  }

  // Prologue: stage superstep 0; prefetch x/scales for superstep 0.
  STAGE(0, 0)
  bf16x8 acur[8], anext[8];
  LOADX(acur, 0)
  f32x4 sc = *reinterpret_cast<const f32x4*>(srow);

#pragma unroll 1
  for (int t = 0; t < NSTEP - 1; ++t) {
    LOADX(anext, t + 1)                                  // 8 vmem
    f32x4 sn = *reinterpret_cast<const f32x4*>(srow + (t + 1) * 4);  // 1 vmem
    STAGE(t + 1, (t + 1) & 1)                            // 16 vmem
    asm volatile("s_waitcnt vmcnt(25)" ::: "memory");    // superstep t landed
    __builtin_amdgcn_sched_barrier(0);
    COMPUTE(t & 1, acur, sc)
#pragma unroll
    for (int kk = 0; kk < 8; ++kk) acur[kk] = anext[kk];
    sc = sn;
  }
  asm volatile("s_waitcnt vmcnt(0)" ::: "memory");
  __builtin_amdgcn_sched_barrier(0);
  COMPUTE((NSTEP - 1) & 1, acur, sc)

#undef STAGE
#undef COMPUTE
#undef LOADX

  // ---- split-K reduction: alias red[] into (now dead) qbuf ----
  __syncthreads();                                  // all waves done with qbuf
  float* red = reinterpret_cast<float*>(smem);      // [KSPLIT][64][4] = 4KB
#pragma unroll
  for (int r = 0; r < 4; ++r) red[(w * 64 + lane) * 4 + r] = acc[r];
  __syncthreads();
  if (threadIdx.x >= 64) return;

  f32x4 tot = {0.f, 0.f, 0.f, 0.f};
#pragma unroll
  for (int ww = 0; ww < KSPLIT; ++ww)
    tot += *reinterpret_cast<const f32x4*>(red + (ww * 64 + lane) * 4);

  // ---- LoRA epilogue: reduce t partials for this lane's fragment, 1 MFMA ----
  f32x4 t0 = {0.f,0.f,0.f,0.f}, t1 = {0.f,0.f,0.f,0.f};
#pragma unroll
  for (int c = 0; c < TCHUNK; ++c) {
    const f32x4* pc = reinterpret_cast<const f32x4*>(
        part + (size_t)c * (M_TOK * RANK) + col * RANK + hi * 8);
    t0 += pc[0];
    t1 += pc[1];
  }
  f32x4 u0 = *reinterpret_cast<const f32x4*>(lu + (size_t)o * RANK + hi * 8);
  f32x4 u1 = *reinterpret_cast<const f32x4*>(lu + (size_t)o * RANK + hi * 8 + 4);
  bf16x8 ta, lb;
#pragma unroll
  for (int j = 0; j < 4; ++j) {
    ta[j]     = (__bf16)t0[j];
    ta[j + 4] = (__bf16)t1[j];
    lb[j]     = (__bf16)u0[j];
    lb[j + 4] = (__bf16)u1[j];
  }
  f32x4 lacc = {0.f, 0.f, 0.f, 0.f};
  lacc = __builtin_amdgcn_mfma_f32_16x16x32_bf16(ta, lb, lacc, 0, 0, 0);

  const float bv = bias[o];
#pragma unroll
  for (int reg = 0; reg < 4; ++reg) {
    const int m = hi * 4 + reg;
    out[(size_t)m * OUT_F + o] = tot[reg] + lacc[reg] + bv;
  }
}

extern "C" void kernel_launch(void* const* d_in, const int* in_sizes, int n_in,
                              void* d_out, int out_size, void* d_ws, size_t ws_size,
                              hipStream_t stream) {
  const float* x    = (const float*)d_in[0];
  const int*   qw   = (const int*)d_in[1];
  const float* wsc  = (const float*)d_in[2];
  const float* ld   = (const float*)d_in[3];
  const float* lu   = (const float*)d_in[4];
  const float* bias = (const float*)d_in[5];
  float*       out  = (float*)d_out;

  float*  part = (float*)d_ws;                          // 16*512 f32 = 32 KB
  __bf16* xbf  = (__bf16*)((char*)d_ws + 64 * 1024);    // 256 KB

  svdq_prep<<<TCHUNK, 512, 0, stream>>>(x, ld, part, xbf);
  svdq_main<<<OUT_F / 16, 256, 0, stream>>>(xbf, qw, wsc, lu, bias, part, out);
}